// Round 11
// baseline (388.359 us; speedup 1.0000x reference)
//
#include <hip/hip_runtime.h>
#include <hip/hip_bf16.h>

#define NGRID 70144
#define NV 128

typedef float f32x4 __attribute__((ext_vector_type(4)));
typedef short short8 __attribute__((ext_vector_type(8)));

__device__ __forceinline__ unsigned f2bf(float f){
  return (unsigned)__bfloat16_as_ushort(__float2bfloat16(f));   // RNE
}
__device__ __forceinline__ float bf2f(unsigned h){ return __uint_as_float(h<<16); }
__device__ __forceinline__ unsigned packsplit(float f){
  unsigned h = f2bf(f);
  unsigned l = f2bf(f - bf2f(h));
  return (h<<16) | l;
}

// ---------- compile-time tables ----------
// Tile = (ring, type=re/im, v-half): 4 uniform variants per ring, full M span.
// XCD-grouped: all variants of a ring at dispatch index == q (mod 8).
struct TileT { unsigned char ring, type, vh; };
constexpr int NTILES = 512;
struct Tiles { TileT t[NTILES]; };
constexpr Tiles make_tiles(){
  Tiles T{}; int k=0;
  for(int g=0; g<16; g++){                     // heavy rings first
    for(int var=0; var<4; var++)
      for(int q=0; q<8; q++){
        int r = 127-(g*8+q);
        T.t[k].ring=(unsigned char)r;
        T.t[k].type=(unsigned char)(var>>1);
        T.t[k].vh  =(unsigned char)(var&1);
        k++;
      }
  }
  return T;
}
__constant__ Tiles TILES = make_tiles();

struct Offs { long o[129]; };
constexpr Offs make_offs(){
  Offs O{}; long off=0;
  for(int r=0;r<128;r++){
    O.o[r]=off;
    int mh=(5+r<128)?(5+r):128, jc=11+2*r;
    off += 4L*(((mh+15)/16)*16)*(((jc+31)/32)*32);
  }
  O.o[128]=off;
  return O;
}
__constant__ Offs TWOFF = make_offs();
constexpr long TWATOT = make_offs().o[128];

// Padded per-ring twiddle slabs: [cos_hi|cos_lo|sin_hi|sin_lo][Mpad][Kpad] bf16.
__global__ void fill_tw(unsigned short* __restrict__ twA){
  int ring = blockIdx.x, t = blockIdx.y, mq = blockIdx.z;   // m-split x4
  int N = 20+4*ring, H = N/2, JC = H+1;
  int mhi = (5+ring<128)?(5+ring):128;
  int Mpad = ((mhi+15)>>4)<<4;
  int Kpad = ((JC+31)>>5)<<5;
  long MK = (long)Mpad*Kpad;
  unsigned short* hiT = twA + TWOFF.o[ring] + (long)(t*2)*MK;
  unsigned short* loT = hiT + MK;
  float invN = 1.0f/(float)N;
  int tid = threadIdx.x;
  for(int m=mq; m<Mpad; m+=4){
    int p0   = (int)(((long)m*tid) % N);
    int step = (int)(((long)m*256) % N);
    int p = p0;
    for(int j=tid;j<Kpad;j+=256){
      float val = 0.f;
      if(m < mhi && j < JC){
        float th = 6.2831853071795864f * (float)p * invN;
        float sn, cs; __sincosf(th,&sn,&cs);
        val = (t ? -sn : cs) * invN;
      }
      unsigned h = f2bf(val);
      unsigned l = f2bf(val - bf2f(h));
      long idx = (long)m*Kpad + j;
      hiT[idx] = (unsigned short)h;
      loT[idx] = (unsigned short)l;
      p += step; if(p>=N) p-=N;
    }
  }
}

// Folded ragged DFT as split-bf16 MFMA GEMM.
// BARRIER-FREE: each lane builds its own B-fragment directly from x
// (LDS staging was pure redistribution — zero cross-lane reuse).
// Gp layout: [s][m][n=ring][b][2v+ri] u32-packed (hi<<16|lo).
__global__ __launch_bounds__(256,3) void dft_mfma(const float* __restrict__ x,
                                                  const unsigned short* __restrict__ twA,
                                                  unsigned* __restrict__ Gp){
  TileT tl = TILES.t[blockIdx.x];
  int ring = tl.ring, type = tl.type, vh = tl.vh;
  int b = blockIdx.y;
  int N = 20+4*ring, H = N/2, JC = H+1;
  int mhi = (5+ring<128)?(5+ring):128;
  int MtN = (mhi+15)>>4;
  int KT = (JC+31)>>5;
  int Kpad = KT<<5;
  int Mpad = MtN<<4;

  long MK = (long)Mpad*Kpad;
  const unsigned short* Ahi = twA + TWOFF.o[ring] + (long)(type*2)*MK;
  const unsigned short* Alo = Ahi + MK;

  const float* xn = x + ((long)b*NGRID + (long)ring*(2*ring+18))*NV;
  long a1 = ring+1;
  const float* xs = x + ((long)b*NGRID + (NGRID - a1*(2*a1+18)))*NV;

  int lane = threadIdx.x & 63, wave = threadIdx.x >> 6;
  int jj = lane & 15, kb = lane >> 4;

  // lane's two columns: cg = vh*128 + wave*32 + ct*16 + jj ; v=cg>>1, par=cg&1
  int cg0 = vh*128 + wave*32 + jj;
  int v0 = cg0 >> 1,        par0 = cg0 & 1;
  int v1 = (cg0+16) >> 1,   par1 = (cg0+16) & 1;

  f32x4 acc[8][2];
  #pragma unroll
  for(int Mt=0;Mt<8;Mt++){ acc[Mt][0]=(f32x4){0.f,0.f,0.f,0.f}; acc[Mt][1]=(f32x4){0.f,0.f,0.f,0.f}; }

  for(int kt=0; kt<KT; ++kt){
    short8 bh[2], bl[2];
    #pragma unroll
    for(int ct=0;ct<2;ct++){
      int v  = ct ? v1 : v0;
      int par= ct ? par1 : par0;
      #pragma unroll
      for(int e=0;e<8;e++){
        int j = kt*32 + kb*8 + e;
        float vn=0.f, vs=0.f, vpn=0.f, vps=0.f;
        if(j < JC){
          vn = xn[(long)j*NV + v];
          vs = xs[(long)j*NV + v];
          if(j > 0 && j < H){
            int jp = N - j;
            vpn = xn[(long)jp*NV + v];
            vps = xs[(long)jp*NV + v];
          }
        }
        float base = par ? (vn - vs) : (vn + vs);
        float mirr = par ? (vpn - vps) : (vpn + vps);
        float val  = type ? (base - mirr) : (base + mirr);
        unsigned h = f2bf(val);
        unsigned lo = f2bf(val - bf2f(h));
        bh[ct][e] = (short)h;
        bl[ct][e] = (short)lo;
      }
    }
    #pragma unroll
    for(int Mt=0;Mt<8;Mt++){
      if(Mt < MtN){
        long ao = (long)(Mt*16 + jj)*Kpad + kt*32 + kb*8;
        short8 ah = *(const short8*)&Ahi[ao];
        short8 al = *(const short8*)&Alo[ao];
        #pragma unroll
        for(int ct=0;ct<2;ct++){
          acc[Mt][ct] = __builtin_amdgcn_mfma_f32_16x16x32_bf16(ah, bh[ct], acc[Mt][ct], 0,0,0);
          acc[Mt][ct] = __builtin_amdgcn_mfma_f32_16x16x32_bf16(al, bh[ct], acc[Mt][ct], 0,0,0);
          acc[Mt][ct] = __builtin_amdgcn_mfma_f32_16x16x32_bf16(ah, bl[ct], acc[Mt][ct], 0,0,0);
        }
      }
    }
  }
  // ---- epilogue: D col=jj (==cg col), row=kb*4+reg ----
  #pragma unroll
  for(int Mt=0;Mt<8;Mt++){
    if(Mt < MtN){
      #pragma unroll
      for(int ct=0;ct<2;ct++){
        int cg = cg0 + ct*16;
        int s = cg & 1, v = cg >> 1;
        #pragma unroll
        for(int reg=0;reg<4;reg++){
          int m = Mt*16 + (kb<<2) + reg;
          if(m < mhi){
            Gp[(((long)(s*128 + m)*128 + ring)*1024) + b*256 + v*2 + type]
              = packsplit(acc[Mt][ct][reg]);
          }
        }
      }
    }
  }
}

// Split W (fp32) into bf16 hi/lo tables. Layout [s][m][l][n] flat.
__global__ void w_split(const float* __restrict__ Wsym, const float* __restrict__ Want,
                        unsigned short* __restrict__ Wh, unsigned short* __restrict__ Wl){
  long i = (long)blockIdx.x*256 + threadIdx.x;   // 0 .. 2*1048576-1
  const float* W = (i < 1048576) ? Wsym : Want;
  float w = W[i & 1048575];
  unsigned h = f2bf(w);
  unsigned l = f2bf(w - bf2f(h));
  Wh[i] = (unsigned short)h;
  Wl[i] = (unsigned short)l;
}

// Per-(m,b,s) Legendre matmul via split-bf16 MFMA.
// BARRIER-FREE: each lane loads its own B-fragment directly from Gp.
__global__ __launch_bounds__(256,3) void legendre_mfma(const unsigned short* __restrict__ Wh,
                                                       const unsigned short* __restrict__ Wl,
                                                       const unsigned* __restrict__ Gp,
                                                       float* __restrict__ out){
  int m = blockIdx.x, b = blockIdx.y, s = blockIdx.z;
  int lane = threadIdx.x & 63, wave = threadIdx.x >> 6;
  int jj = lane & 15, kb = lane >> 4;

  int kt0 = (m > 4) ? ((m-4) >> 5) : 0;         // W[m][l][n]==0 for n<m-4

  const unsigned short* WA = Wh + (long)(s*128+m)*8192;   // [l][n] 64x128
  const unsigned short* WB = Wl + (long)(s*128+m)*8192;
  long gBase = ((long)(s*128 + m)*128)*1024 + b*256;       // + n*1024 + c

  f32x4 acc[4][4];
  #pragma unroll
  for(int a=0;a<4;a++)
    #pragma unroll
    for(int q=0;q<4;q++) acc[a][q] = (f32x4){0.f,0.f,0.f,0.f};

  for(int kt=kt0; kt<4; ++kt){
    short8 bh[4], bl[4];
    #pragma unroll
    for(int nt=0;nt<4;nt++){
      int c = (wave*4+nt)*16 + jj;
      #pragma unroll
      for(int e=0;e<8;e++){
        int n = kt*32 + kb*8 + e;
        unsigned p = Gp[gBase + (long)n*1024 + c];
        bh[nt][e] = (short)(p >> 16);
        bl[nt][e] = (short)(p & 0xFFFFu);
      }
    }
    #pragma unroll
    for(int Mt=0;Mt<4;Mt++){
      long ao = (long)(Mt*16 + jj)*128 + kt*32 + kb*8;
      short8 ah = *(const short8*)&WA[ao];
      short8 al = *(const short8*)&WB[ao];
      #pragma unroll
      for(int nt=0;nt<4;nt++){
        acc[Mt][nt] = __builtin_amdgcn_mfma_f32_16x16x32_bf16(ah, bh[nt], acc[Mt][nt], 0,0,0);
        acc[Mt][nt] = __builtin_amdgcn_mfma_f32_16x16x32_bf16(al, bh[nt], acc[Mt][nt], 0,0,0);
        acc[Mt][nt] = __builtin_amdgcn_mfma_f32_16x16x32_bf16(ah, bl[nt], acc[Mt][nt], 0,0,0);
      }
    }
  }
  int r4 = (lane>>4)<<2;
  #pragma unroll
  for(int Mt=0;Mt<4;Mt++){
    #pragma unroll
    for(int nt=0;nt<4;nt++){
      int c = (wave*4+nt)*16 + jj;
      #pragma unroll
      for(int reg=0;reg<4;reg++){
        int l = Mt*16 + r4 + reg;
        out[((long)(b*128 + 2*l + s)*128 + m)*256 + c] = acc[Mt][nt][reg];
      }
    }
  }
}

extern "C" void kernel_launch(void* const* d_in, const int* in_sizes, int n_in,
                              void* d_out, int out_size, void* d_ws, size_t ws_size,
                              hipStream_t stream) {
  const float* x    = (const float*)d_in[0];
  const float* Wsym = (const float*)d_in[1];
  const float* Want = (const float*)d_in[2];
  float* out = (float*)d_out;

  size_t gpOffB = (size_t)TWATOT*2;
  if(gpOffB < 8388608) gpOffB = 8388608;        // keep room for Wh/Wl overlap
  gpOffB = (gpOffB + 255) & ~(size_t)255;

  unsigned short* twA = (unsigned short*)d_ws;
  unsigned* Gp = (unsigned*)((char*)d_ws + gpOffB);     // 134 MB packed G
  unsigned short* Wh = (unsigned short*)d_ws;           // overlaps twA (dead after dft)
  unsigned short* Wl = Wh + 2097152;

  hipLaunchKernelGGL(fill_tw,       dim3(128,2,4),   dim3(256), 0, stream, twA);
  hipLaunchKernelGGL(dft_mfma,      dim3(NTILES,4),  dim3(256), 0, stream, x, twA, Gp);
  hipLaunchKernelGGL(w_split,       dim3(8192),      dim3(256), 0, stream, Wsym, Want, Wh, Wl);
  hipLaunchKernelGGL(legendre_mfma, dim3(128,4,2),   dim3(256), 0, stream, Wh, Wl, Gp, out);
}